// Round 1
// baseline (323.397 us; speedup 1.0000x reference)
//
#include <hip/hip_runtime.h>

// MLA forward: out = softmax_causal( rope(x@Wq) @ rope(x@Wk)^T / sqrt(192) ) @ (x@Wv) @ Wo + bo
// Strategy: bf16 MFMA everywhere (threshold is 2% of max|ref|), fp32 accumulation.

typedef __bf16 bf16;
typedef __bf16 bf16x8 __attribute__((ext_vector_type(8)));
typedef __bf16 bf16x4 __attribute__((ext_vector_type(4)));
typedef float  f32x4  __attribute__((ext_vector_type(4)));

#define DEVI __device__ __forceinline__

static constexpr int Bc = 2, Sc = 1024, DIMc = 2048, Hc = 16;
static constexpr int NOPEc = 128, QKDc = 192, VDc = 128;
static constexpr int Mrows = Bc * Sc;          // 2048
static constexpr int NQ    = Hc * QKDc;        // 3072
static constexpr int NCAT  = NQ + NQ + Hc*VDc; // 8192  [Q | K | V] per row

// ---------------- fp32 -> bf16 convert (vectorized) ----------------
__global__ __launch_bounds__(256) void k_cvt(const float* __restrict__ in, bf16* __restrict__ out) {
    int i = (blockIdx.x * 256 + threadIdx.x) * 8;
    float4 a = *(const float4*)(in + i);
    float4 b = *(const float4*)(in + i + 4);
    bf16x8 o;
    o[0]=(bf16)a.x; o[1]=(bf16)a.y; o[2]=(bf16)a.z; o[3]=(bf16)a.w;
    o[4]=(bf16)b.x; o[5]=(bf16)b.y; o[6]=(bf16)b.z; o[7]=(bf16)b.w;
    *(bf16x8*)(out + i) = o;
}

// ---------------- transpose + convert: in (K x N) fp32 -> out (N x K=2048) bf16 ----------------
__global__ __launch_bounds__(256) void k_transpose(const float* __restrict__ in, bf16* __restrict__ out, int N) {
    __shared__ float tile[64][68];   // +4 pad: conflict-free
    int k0 = blockIdx.x * 64, n0 = blockIdx.y * 64;
    int tr = threadIdx.x >> 4, tc = (threadIdx.x & 15) * 4;
#pragma unroll
    for (int i = 0; i < 4; i++) {
        int r = tr + i * 16;
        float4 v = *(const float4*)(in + (size_t)(k0 + r) * N + n0 + tc);
        tile[r][tc+0] = v.x; tile[r][tc+1] = v.y; tile[r][tc+2] = v.z; tile[r][tc+3] = v.w;
    }
    __syncthreads();
#pragma unroll
    for (int i = 0; i < 4; i++) {
        int n = tr + i * 16;
        bf16x4 o;
#pragma unroll
        for (int j = 0; j < 4; j++) o[j] = (bf16)tile[tc + j][n];
        *(bf16x4*)(out + (size_t)(n0 + n) * 2048 + k0 + tc) = o;
    }
}

// ---------------- RoPE cos/sin table: [S][32] each ----------------
__global__ void k_ropetab(float* __restrict__ cosT, float* __restrict__ sinT) {
    int idx = blockIdx.x * 256 + threadIdx.x;  // S*32 = 32768
    int pos = idx >> 5, i = idx & 31;
    float theta = expf(-(float)i * (9.210340371976184f / 32.0f)); // 10000^(-i/32)
    float ang = (float)pos * theta;
    cosT[idx] = cosf(ang);
    sinT[idx] = sinf(ang);
}

// ---------------- RoPE apply in-place on bf16 QKV rows ----------------
__global__ __launch_bounds__(256) void k_rope(bf16* __restrict__ qkv, const float* __restrict__ cosT,
                                              const float* __restrict__ sinT, int secbase) {
    int idx = blockIdx.x * 256 + threadIdx.x;  // B*S*H*8 = 262144
    int g = idx & 7, h = (idx >> 3) & 15, row = idx >> 7;   // row = b*S+s
    int s = row & (Sc - 1);
    bf16* p = qkv + (size_t)row * NCAT + secbase + h * QKDc + NOPEc + g * 8;
    bf16x8 v = *(bf16x8*)p;
    const float* cp = cosT + s * 32 + g * 4;
    const float* sp = sinT + s * 32 + g * 4;
#pragma unroll
    for (int q = 0; q < 4; q++) {
        float x0 = (float)v[2*q], x1 = (float)v[2*q+1];
        float c = cp[q], sn = sp[q];
        v[2*q]   = (bf16)(x0 * c - x1 * sn);
        v[2*q+1] = (bf16)(x1 * c + x0 * sn);
    }
    *(bf16x8*)p = v;
}

// ---------------- m97-style 128x128 GEMM: C = A(MxK) * Bt(NxK)^T ----------------
DEVI void gload16(const bf16* g, bf16* l) {
    __builtin_amdgcn_global_load_lds((const __attribute__((address_space(1))) void*)g,
                                     (__attribute__((address_space(3))) void*)l, 16, 0, 0);
}

template<bool OUT_BF16, bool BIAS>
__global__ __launch_bounds__(256) void k_gemm(const bf16* __restrict__ A, const bf16* __restrict__ Bt,
                                              void* __restrict__ Cptr, const float* __restrict__ bias,
                                              int N, int K) {
    __shared__ __align__(16) bf16 As[128 * 32];
    __shared__ __align__(16) bf16 Bs[128 * 32];
    const int tid = threadIdx.x;
    const int l = tid & 63, w = tid >> 6;
    const int lg = l >> 4, lc = l & 15;
    const int wr = (w >> 1) * 64, wc = (w & 1) * 64;
    const int row0 = blockIdx.x * 128, col0 = blockIdx.y * 128;
    const int srow = tid >> 2, sseg = (tid & 3) * 8;      // LDS dest = uniform + lane*16B
    const bf16* Ag = A  + (size_t)(row0 + srow) * K + sseg;
    const bf16* Bg = Bt + (size_t)(col0 + srow) * K + sseg;
    bf16* Asl = As + srow * 32 + sseg;
    bf16* Bsl = Bs + srow * 32 + sseg;
    f32x4 acc[4][4] = {};
    for (int kt = 0; kt < K; kt += 32) {
        __syncthreads();
        gload16(Ag,          Asl);
        gload16(Ag + 64 * K, Asl + 64 * 32);
        gload16(Bg,          Bsl);
        gload16(Bg + 64 * K, Bsl + 64 * 32);
        Ag += 32; Bg += 32;
        __syncthreads();
        bf16x8 aF[4], bF[4];
#pragma unroll
        for (int m = 0; m < 4; m++) aF[m] = *(const bf16x8*)(As + (wr + m * 16 + lc) * 32 + lg * 8);
#pragma unroll
        for (int n = 0; n < 4; n++) bF[n] = *(const bf16x8*)(Bs + (wc + n * 16 + lc) * 32 + lg * 8);
#pragma unroll
        for (int m = 0; m < 4; m++)
#pragma unroll
            for (int n = 0; n < 4; n++)
                acc[m][n] = __builtin_amdgcn_mfma_f32_16x16x32_bf16(aF[m], bF[n], acc[m][n], 0, 0, 0);
    }
#pragma unroll
    for (int m = 0; m < 4; m++)
#pragma unroll
        for (int n = 0; n < 4; n++)
#pragma unroll
            for (int j = 0; j < 4; j++) {
                int r = row0 + wr + m * 16 + lg * 4 + j;   // D row = (lane>>4)*4 + reg  [m89/m91]
                int c = col0 + wc + n * 16 + lc;           // D col = lane&15
                float v = acc[m][n][j];
                if (BIAS) v += bias[c];
                if (OUT_BF16) ((bf16*)Cptr)[(size_t)r * N + c] = (bf16)v;
                else          ((float*)Cptr)[(size_t)r * N + c] = v;
            }
}

// ---------------- flash attention: 64 q-rows per block (4 waves x 16 rows), 64-wide KV chunks ----------------
__global__ __launch_bounds__(256) void k_attn(const bf16* __restrict__ qkv, bf16* __restrict__ cv) {
    const int qt = blockIdx.x;   // q-tile 0..15
    const int bh = blockIdx.y;   // b*H + h
    const int b = bh >> 4, h = bh & 15;
    const int tid = threadIdx.x, l = tid & 63, w = tid >> 6;
    const int lg = l >> 4, lc = l & 15;
    __shared__ __align__(16) bf16 VT[128][72];      // V^T chunk, +8 pad -> 144B rows (2-way only)
    __shared__ __align__(16) bf16 Pl[4][16][72];    // per-wave P tile
    const bf16* Qb = qkv + (size_t)b * Sc * NCAT + h * QKDc;
    const bf16* Kb = Qb + NQ;
    const bf16* Vb = qkv + (size_t)b * Sc * NCAT + 2 * NQ + h * VDc;

    // Q fragments held in registers for the whole kernel (A operand: lane -> row lc, k-slice lg*8)
    bf16x8 qF[6];
    const int qrow = qt * 64 + w * 16 + lc;
#pragma unroll
    for (int kc = 0; kc < 6; kc++) qF[kc] = *(const bf16x8*)(Qb + (size_t)qrow * NCAT + kc * 32 + lg * 8);

    f32x4 acc[8] = {};
    float mrow[4] = {-1e30f, -1e30f, -1e30f, -1e30f};
    float lsum[4] = {0.f, 0.f, 0.f, 0.f};
    const float scale = 0.07216878364870323f;  // 192^-0.5

    for (int c = 0; c <= qt; ++c) {
        const int t0 = c * 64;
        __syncthreads();   // protect VT from previous chunk's readers
        {   // stage V^T: coalesced 16B reads, transposed b16 writes
            const int dseg = tid & 15, trow = tid >> 4;
#pragma unroll
            for (int i = 0; i < 4; i++) {
                int t = trow + i * 16;
                bf16x8 v = *(const bf16x8*)(Vb + (size_t)(t0 + t) * NCAT + dseg * 8);
#pragma unroll
                for (int jj = 0; jj < 8; jj++) VT[dseg * 8 + jj][t] = v[jj];
            }
        }
        __syncthreads();
        // scores: D[r][t] = sum_d Q[r][d] K[t][d]  (K frags straight from L2)
        f32x4 sc[4] = {};
#pragma unroll
        for (int nt = 0; nt < 4; nt++)
#pragma unroll
            for (int kc = 0; kc < 6; kc++) {
                bf16x8 kf = *(const bf16x8*)(Kb + (size_t)(t0 + nt * 16 + lc) * NCAT + kc * 32 + lg * 8);
                sc[nt] = __builtin_amdgcn_mfma_f32_16x16x32_bf16(qF[kc], kf, sc[nt], 0, 0, 0);
            }
        // scale + causal mask + online softmax
        float p[4][4];
        float cmax[4] = {-1e30f, -1e30f, -1e30f, -1e30f};
        const bool diag = (c == qt);
#pragma unroll
        for (int nt = 0; nt < 4; nt++)
#pragma unroll
            for (int j = 0; j < 4; j++) {
                float v = sc[nt][j] * scale;
                if (diag) {
                    int tg = t0 + nt * 16 + lc;
                    int rg = qt * 64 + w * 16 + lg * 4 + j;
                    if (tg > rg) v = -1e9f;
                }
                p[nt][j] = v;
                cmax[j] = fmaxf(cmax[j], v);
            }
#pragma unroll
        for (int j = 0; j < 4; j++)
#pragma unroll
            for (int d = 1; d < 16; d <<= 1) cmax[j] = fmaxf(cmax[j], __shfl_xor(cmax[j], d));
        float f[4];
#pragma unroll
        for (int j = 0; j < 4; j++) {
            float nm = fmaxf(mrow[j], cmax[j]);
            f[j] = __expf(mrow[j] - nm);
            mrow[j] = nm;
        }
        float psum[4] = {0.f, 0.f, 0.f, 0.f};
#pragma unroll
        for (int nt = 0; nt < 4; nt++)
#pragma unroll
            for (int j = 0; j < 4; j++) {
                p[nt][j] = __expf(p[nt][j] - mrow[j]);
                psum[j] += p[nt][j];
            }
#pragma unroll
        for (int j = 0; j < 4; j++) {
#pragma unroll
            for (int d = 1; d < 16; d <<= 1) psum[j] += __shfl_xor(psum[j], d);
            lsum[j] = lsum[j] * f[j] + psum[j];
        }
#pragma unroll
        for (int n = 0; n < 8; n++)
#pragma unroll
            for (int j = 0; j < 4; j++) acc[n][j] *= f[j];
        // P -> LDS (D layout) then re-read as A fragments
#pragma unroll
        for (int nt = 0; nt < 4; nt++)
#pragma unroll
            for (int j = 0; j < 4; j++)
                Pl[w][lg * 4 + j][nt * 16 + lc] = (bf16)p[nt][j];
#pragma unroll
        for (int ks = 0; ks < 2; ks++) {
            bf16x8 aP = *(const bf16x8*)(&Pl[w][lc][ks * 32 + lg * 8]);
#pragma unroll
            for (int n = 0; n < 8; n++) {
                bf16x8 bV = *(const bf16x8*)(&VT[n * 16 + lc][ks * 32 + lg * 8]);
                acc[n] = __builtin_amdgcn_mfma_f32_16x16x32_bf16(aP, bV, acc[n], 0, 0, 0);
            }
        }
    }
    // epilogue: O /= lsum, write (B,S,H,VD) bf16
#pragma unroll
    for (int j = 0; j < 4; j++) {
        float inv = 1.0f / lsum[j];
        int r = qt * 64 + w * 16 + lg * 4 + j;
#pragma unroll
        for (int n = 0; n < 8; n++) {
            float v = acc[n][j] * inv;
            cv[((size_t)(b * Sc + r) * Hc + h) * VDc + n * 16 + lc] = (bf16)v;
        }
    }
}

// ---------------- launch ----------------
extern "C" void kernel_launch(void* const* d_in, const int* in_sizes, int n_in,
                              void* d_out, int out_size, void* d_ws, size_t ws_size,
                              hipStream_t stream) {
    const float* x  = (const float*)d_in[0];
    const float* Wq = (const float*)d_in[1];
    const float* Wk = (const float*)d_in[2];
    const float* Wv = (const float*)d_in[3];
    const float* Wo = (const float*)d_in[4];
    const float* bo = (const float*)d_in[5];
    float* out = (float*)d_out;
    char* ws = (char*)d_ws;

    // workspace layout (bytes)
    bf16*  wcat = (bf16*)(ws + 0);          // 8192x2048 bf16 = 33554432
    bf16*  woT  = (bf16*)(ws + 33554432);   // 2048x2048 bf16 =  8388608
    bf16*  xb   = (bf16*)(ws + 41943040);   // 2048x2048 bf16 =  8388608
    bf16*  qkvb = (bf16*)(ws + 50331648);   // 2048x8192 bf16 = 33554432
    bf16*  cvb  = (bf16*)(ws + 83886080);   // 2048x2048 bf16 =  8388608
    float* cosT = (float*)(ws + 92274688);  // 1024x32 f32    =   131072
    float* sinT = (float*)(ws + 92405760);  // 1024x32 f32    =   131072
    // total: 92536832 bytes (~88.3 MiB)

    k_cvt<<<2048, 256, 0, stream>>>(x, xb);
    k_transpose<<<dim3(32, 48), 256, 0, stream>>>(Wq, wcat, 3072);
    k_transpose<<<dim3(32, 48), 256, 0, stream>>>(Wk, wcat + (size_t)3072 * 2048, 3072);
    k_transpose<<<dim3(32, 32), 256, 0, stream>>>(Wv, wcat + (size_t)6144 * 2048, 2048);
    k_transpose<<<dim3(32, 32), 256, 0, stream>>>(Wo, woT, 2048);
    k_ropetab<<<128, 256, 0, stream>>>(cosT, sinT);
    // fused QKV projection: (2048x2048) x (8192x2048)^T -> (2048x8192) bf16
    k_gemm<true, false><<<dim3(16, 64), 256, 0, stream>>>(xb, wcat, qkvb, nullptr, NCAT, DIMc);
    k_rope<<<1024, 256, 0, stream>>>(qkvb, cosT, sinT, 0);     // Q section
    k_rope<<<1024, 256, 0, stream>>>(qkvb, cosT, sinT, NQ);    // K section
    k_attn<<<dim3(16, 32), 256, 0, stream>>>(qkvb, cvb);
    // output projection with bias: (2048x2048) x (2048x2048)^T -> fp32 out
    k_gemm<false, true><<<dim3(16, 16), 256, 0, stream>>>(cvb, woT, out, bo, DIMc, DIMc);
}